// Round 18
// baseline (379.038 us; speedup 1.0000x reference)
//
#include <hip/hip_runtime.h>

#define NB_HG 2048   // H*G = 32*64
#define DIM_N 128
#define DIM_D 128
#define DIM_S 256

// Numerics: golden = per-element strictly sequential ascending-d fp32 FMA over
// the SELECTED d's only (masked-out terms exact zeros). Verified bit-exact
// rounds 4-17. One block per hg: stage full X once (swizzled, verified
// conflict-free r5-17), build din/dout lists, then per-wave passes with a
// WAVE-UNIFORM s-window (32 s): b is fetched via readfirstlane + uniform
// address -> SMEM (s_load) into SGPRs, broadcast into FMAs. No vector-memory
// and no LDS traffic for b (R17 post-mortem: per-thread b reads = 4.3 GB of
// L2 traffic = 125 us floor). X: one ds_read_b64 per lane per iter (lanes
// cover the 512B row contiguously -> conflict-free through the XOR swizzle).
// Chain per output unchanged: ascending selected d.

__global__ void transpose_proj_kernel(const float* __restrict__ proj,
                                      float* __restrict__ projT)
{
    const int d = blockIdx.x;                      // 128
    const int s = threadIdx.x;                     // 256
    projT[d * DIM_S + s] = proj[s * DIM_D + d];    // coalesced write
}

template<bool TP>
__global__ __launch_bounds__(256)
void qjl_sketch_kernel(const float* __restrict__ data,
                       const float* __restrict__ mask,
                       const float* __restrict__ pmat,   // TP ? projT[d][s] : proj[s][d]
                       int* __restrict__ out)
{
    __shared__ float Xt[DIM_D * DIM_N];            // 64 KB: full X tile, swizzled
    __shared__ int   din[DIM_D];                   // inlier d's, ascending
    __shared__ int   dout[DIM_D];                  // outlier d's, ascending
    __shared__ int   win[2];                       // per-wave inlier counts

    const int hg  = blockIdx.x;
    const int tid = threadIdx.x;
    const int l   = tid & 63;                      // lane
    const int w   = tid >> 6;                      // wave 0..3

    // ---------- build both compacted ascending d-lists ----------
    bool is_in = false; int rank_in = 0;
    if (tid < 128) {                               // waves 0,1 only (whole waves)
        const float m = mask[hg * DIM_D + tid];    // exactly 0.0f or 1.0f
        is_in = (m == 0.0f);
        const unsigned long long bal = __ballot(is_in);
        if (l == 0) win[w] = __popcll(bal);
        rank_in = __popcll(bal & ((1ull << l) - 1ull));
    }
    __syncthreads();
    const int Kin = win[0] + win[1];               // uniform across block
    if (tid < 128) {
        if (is_in) din [rank_in       + (w ? win[0]        : 0)] = tid;
        else       dout[(l - rank_in) + (w ? (64 - win[0]) : 0)] = tid;
    }

    // ---------- stage FULL X tile, transposed + swizzled ----------
    {
        const int d  = tid & 127;
        const int nh = tid >> 7;                   // 0 or 1
        const float* Xs = data + (size_t)hg * (DIM_N * DIM_D) + d;
        const int pcs = 4 * (d & 7);
        float* row = &Xt[d * DIM_N];
        #pragma unroll
        for (int g = 0; g < 16; ++g) {
            const int n0 = g * 8 + nh * 4;         // 4-aligned logical n block
            float4 v;
            v.x = Xs[(size_t)(n0 + 0) * DIM_D];    // coalesced: lanes span d
            v.y = Xs[(size_t)(n0 + 1) * DIM_D];
            v.z = Xs[(size_t)(n0 + 2) * DIM_D];
            v.w = Xs[(size_t)(n0 + 3) * DIM_D];
            *reinterpret_cast<float4*>(&row[n0 ^ pcs]) = v;
        }
    }
    __syncthreads();                               // lists + tile ready; last barrier

    const size_t inl_total = (size_t)NB_HG * DIM_N * 32;   // 8388608
    const size_t orow = (size_t)hg * DIM_N;
    // lane covers logical n = 2l, 2l+1: physical float offset in row dl is
    // ((l>>1) ^ (dl&7))*4 + 2*(l&1)  (float4-chunk XOR swizzle, 8B aligned)
    const int chunk = l >> 1;
    const int sub2  = 2 * (l & 1);

    // one pass: wave-uniform 32-wide s-window; acc[32 s][2 n] in VGPRs
    auto PASS = [&](const int* __restrict__ list, int cnt, int swin,
                    size_t obase, int obytes_per_n) {
        float acc[32][2];
        #pragma unroll
        for (int j = 0; j < 32; ++j) { acc[j][0] = 0.0f; acc[j][1] = 0.0f; }

        #pragma unroll 2
        for (int ci = 0; ci < cnt; ++ci) {         // ascending selected d
            const int dl  = list[ci];              // uniform LDS broadcast
            const int sdg = __builtin_amdgcn_readfirstlane(dl);   // -> SGPR

            // b: 32 floats from a wave-uniform address -> SMEM s_load
            float b[32];
            if (TP) {
                const float* pr = pmat + (size_t)sdg * DIM_S + swin;
                #pragma unroll
                for (int j = 0; j < 32; ++j) b[j] = pr[j];
            } else {
                #pragma unroll
                for (int j = 0; j < 32; ++j)
                    b[j] = pmat[(size_t)(swin + j) * DIM_D + sdg];
            }

            // X: 2 consecutive n via one ds_read_b64 (contiguous per wave)
            const int phys = ((chunk ^ (dl & 7)) << 2) + sub2;
            const float2 q = *reinterpret_cast<const float2*>(&Xt[dl * DIM_N + phys]);

            #pragma unroll
            for (int j = 0; j < 32; ++j) {
                acc[j][0] = fmaf(b[j], q.x, acc[j][0]);   // serial dep: order fixed
                acc[j][1] = fmaf(b[j], q.y, acc[j][1]);
            }
        }

        // sign-pack: 4 output bytes per n (s = swin + 8*byte + bit)
        #pragma unroll
        for (int i = 0; i < 2; ++i) {
            const int n = 2 * l + i;
            #pragma unroll
            for (int byte = 0; byte < 4; ++byte) {
                int v = 0;
                #pragma unroll
                for (int bit = 0; bit < 8; ++bit)
                    if (acc[byte * 8 + bit][i] > 0.0f) v |= (1 << bit);
                out[obase + (size_t)n * obytes_per_n + (swin >> 3) + byte] = v;
            }
        }
    };

    PASS(din,  Kin,          w * 32,       orow * 32,             32);  // inlier lo
    PASS(din,  Kin,          128 + w * 32, orow * 32,             32);  // inlier hi
    PASS(dout, DIM_D - Kin,  w * 32,       inl_total + orow * 16, 16);  // outlier
}

extern "C" void kernel_launch(void* const* d_in, const int* in_sizes, int n_in,
                              void* d_out, int out_size, void* d_ws, size_t ws_size,
                              hipStream_t stream) {
    const float* data = (const float*)d_in[0];   // (1,32,64,128,128) fp32
    const float* mask = (const float*)d_in[1];   // (1,32,64,128) fp32, values {0,1}
    const float* proj = (const float*)d_in[2];   // (256,128) fp32
    int* out = (int*)d_out;                      // 8388608 inlier + 4194304 outlier int32

    const size_t tp_bytes = (size_t)DIM_D * DIM_S * sizeof(float);   // 128 KB
    if (ws_size >= tp_bytes) {
        float* projT = (float*)d_ws;
        transpose_proj_kernel<<<DIM_D, DIM_S, 0, stream>>>(proj, projT);
        qjl_sketch_kernel<true><<<NB_HG, 256, 0, stream>>>(data, mask, projT, out);
    } else {
        qjl_sketch_kernel<false><<<NB_HG, 256, 0, stream>>>(data, mask, proj, out);
    }
}